// Round 1
// baseline (97376.294 us; speedup 1.0000x reference)
//
#include <hip/hip_runtime.h>

// Problem constants
#define Bsz  32
#define Tt   1024
#define INF  256
#define Hh   768
#define OUTF 128

// Block layout per step-kernel launch:
//   blocks [0,96)    : layer0, step t=s        (96 blocks * 8 j-slots = 768 j, 32 b per slot)
//   blocks [96,192)  : layer1, step u=s-1
//   blocks [192,208) : linear, step v=s-2      (16 blocks * 8 = 128 outputs)
// Ring parity: layer L writes hring[t&1], reads hring[(t&1)^1]. c is single-owner, in-place.

__device__ __forceinline__ float dot4(float4 a, float4 b) {
    return a.x * b.x + a.y * b.y + a.z * b.z + a.w * b.w;
}

__device__ __forceinline__ float sigf(float v) {
    return 1.0f / (1.0f + __expf(-v));
}

__global__ __launch_bounds__(256) void lstm_step(
    const float* __restrict__ x,
    const float* __restrict__ Wih0, const float* __restrict__ Whh0,
    const float* __restrict__ bih0, const float* __restrict__ bhh0,
    const float* __restrict__ Wih1, const float* __restrict__ Whh1,
    const float* __restrict__ bih1, const float* __restrict__ bhh1,
    const float* __restrict__ Wlin, const float* __restrict__ blin,
    float* __restrict__ out,
    float* __restrict__ hring0,   // [2][B][H]
    float* __restrict__ c0,       // [B][H]
    float* __restrict__ hring1,   // [2][B][H]
    float* __restrict__ c1,       // [B][H]
    int s)
{
    const int blk = blockIdx.x;
    const int tid = threadIdx.x;
    const int b   = tid & 31;   // batch 0..31
    const int sub = tid >> 5;   // 0..7

    if (blk < 96) {
        // ---------- layer 0, timestep t = s ----------
        const int t = s;
        if (t >= Tt) return;
        const int j = blk * 8 + sub;                 // h-dim 0..767

        const float* xrow  = x + ((size_t)b * Tt + t) * INF;
        const float* hprev = hring0 + (size_t)((t & 1) ^ 1) * Bsz * Hh + (size_t)b * Hh;

        float a0 = 0.f, a1 = 0.f, a2 = 0.f, a3 = 0.f;

        // input-side: K = 256
        {
            const float4* x4 = (const float4*)xrow;
            const float4* w0 = (const float4*)(Wih0 + (size_t)(0 * Hh + j) * INF);
            const float4* w1 = (const float4*)(Wih0 + (size_t)(1 * Hh + j) * INF);
            const float4* w2 = (const float4*)(Wih0 + (size_t)(2 * Hh + j) * INF);
            const float4* w3 = (const float4*)(Wih0 + (size_t)(3 * Hh + j) * INF);
#pragma unroll 4
            for (int k = 0; k < INF / 4; ++k) {
                float4 xv = x4[k];
                a0 += dot4(xv, w0[k]);
                a1 += dot4(xv, w1[k]);
                a2 += dot4(xv, w2[k]);
                a3 += dot4(xv, w3[k]);
            }
        }
        // recurrent-side: K = 768
        {
            const float4* h4 = (const float4*)hprev;
            const float4* w0 = (const float4*)(Whh0 + (size_t)(0 * Hh + j) * Hh);
            const float4* w1 = (const float4*)(Whh0 + (size_t)(1 * Hh + j) * Hh);
            const float4* w2 = (const float4*)(Whh0 + (size_t)(2 * Hh + j) * Hh);
            const float4* w3 = (const float4*)(Whh0 + (size_t)(3 * Hh + j) * Hh);
#pragma unroll 4
            for (int k = 0; k < Hh / 4; ++k) {
                float4 hv = h4[k];
                a0 += dot4(hv, w0[k]);
                a1 += dot4(hv, w1[k]);
                a2 += dot4(hv, w2[k]);
                a3 += dot4(hv, w3[k]);
            }
        }

        const float pi = a0 + bih0[0 * Hh + j] + bhh0[0 * Hh + j];
        const float pf = a1 + bih0[1 * Hh + j] + bhh0[1 * Hh + j];
        const float pg = a2 + bih0[2 * Hh + j] + bhh0[2 * Hh + j];
        const float po = a3 + bih0[3 * Hh + j] + bhh0[3 * Hh + j];

        const float ig = sigf(pi);
        const float fg = sigf(pf);
        const float gg = tanhf(pg);
        const float og = sigf(po);

        const size_t sidx = (size_t)b * Hh + j;
        const float cn = fg * c0[sidx] + ig * gg;
        c0[sidx] = cn;
        hring0[(size_t)(t & 1) * Bsz * Hh + sidx] = og * tanhf(cn);

    } else if (blk < 192) {
        // ---------- layer 1, timestep u = s-1 ----------
        const int u = s - 1;
        if (u < 0 || u >= Tt) return;
        const int j = (blk - 96) * 8 + sub;

        const float* xin   = hring0 + (size_t)(u & 1) * Bsz * Hh + (size_t)b * Hh;       // h1_u
        const float* hprev = hring1 + (size_t)((u & 1) ^ 1) * Bsz * Hh + (size_t)b * Hh; // h2_{u-1}

        float a0 = 0.f, a1 = 0.f, a2 = 0.f, a3 = 0.f;

        // input-side: K = 768 (layer0 output)
        {
            const float4* x4 = (const float4*)xin;
            const float4* w0 = (const float4*)(Wih1 + (size_t)(0 * Hh + j) * Hh);
            const float4* w1 = (const float4*)(Wih1 + (size_t)(1 * Hh + j) * Hh);
            const float4* w2 = (const float4*)(Wih1 + (size_t)(2 * Hh + j) * Hh);
            const float4* w3 = (const float4*)(Wih1 + (size_t)(3 * Hh + j) * Hh);
#pragma unroll 4
            for (int k = 0; k < Hh / 4; ++k) {
                float4 xv = x4[k];
                a0 += dot4(xv, w0[k]);
                a1 += dot4(xv, w1[k]);
                a2 += dot4(xv, w2[k]);
                a3 += dot4(xv, w3[k]);
            }
        }
        // recurrent-side: K = 768
        {
            const float4* h4 = (const float4*)hprev;
            const float4* w0 = (const float4*)(Whh1 + (size_t)(0 * Hh + j) * Hh);
            const float4* w1 = (const float4*)(Whh1 + (size_t)(1 * Hh + j) * Hh);
            const float4* w2 = (const float4*)(Whh1 + (size_t)(2 * Hh + j) * Hh);
            const float4* w3 = (const float4*)(Whh1 + (size_t)(3 * Hh + j) * Hh);
#pragma unroll 4
            for (int k = 0; k < Hh / 4; ++k) {
                float4 hv = h4[k];
                a0 += dot4(hv, w0[k]);
                a1 += dot4(hv, w1[k]);
                a2 += dot4(hv, w2[k]);
                a3 += dot4(hv, w3[k]);
            }
        }

        const float pi = a0 + bih1[0 * Hh + j] + bhh1[0 * Hh + j];
        const float pf = a1 + bih1[1 * Hh + j] + bhh1[1 * Hh + j];
        const float pg = a2 + bih1[2 * Hh + j] + bhh1[2 * Hh + j];
        const float po = a3 + bih1[3 * Hh + j] + bhh1[3 * Hh + j];

        const float ig = sigf(pi);
        const float fg = sigf(pf);
        const float gg = tanhf(pg);
        const float og = sigf(po);

        const size_t sidx = (size_t)b * Hh + j;
        const float cn = fg * c1[sidx] + ig * gg;
        c1[sidx] = cn;
        hring1[(size_t)(u & 1) * Bsz * Hh + sidx] = og * tanhf(cn);

    } else {
        // ---------- final linear, timestep v = s-2 ----------
        const int v = s - 2;
        if (v < 0 || v >= Tt) return;
        const int o = (blk - 192) * 8 + sub;   // 0..127

        const float* h2 = hring1 + (size_t)(v & 1) * Bsz * Hh + (size_t)b * Hh;
        const float4* h4 = (const float4*)h2;
        const float4* w4 = (const float4*)(Wlin + (size_t)o * Hh);

        float acc = 0.f;
#pragma unroll 4
        for (int k = 0; k < Hh / 4; ++k) {
            acc += dot4(h4[k], w4[k]);
        }
        out[((size_t)b * Tt + v) * OUTF + o] = acc + blin[o];
    }
}

extern "C" void kernel_launch(void* const* d_in, const int* in_sizes, int n_in,
                              void* d_out, int out_size, void* d_ws, size_t ws_size,
                              hipStream_t stream)
{
    const float* x    = (const float*)d_in[0];
    const float* Wih0 = (const float*)d_in[1];
    const float* Whh0 = (const float*)d_in[2];
    const float* bih0 = (const float*)d_in[3];
    const float* bhh0 = (const float*)d_in[4];
    const float* Wih1 = (const float*)d_in[5];
    const float* Whh1 = (const float*)d_in[6];
    const float* bih1 = (const float*)d_in[7];
    const float* bhh1 = (const float*)d_in[8];
    const float* Wlin = (const float*)d_in[9];
    const float* blin = (const float*)d_in[10];
    float* out = (float*)d_out;

    // Workspace carve-up (all fp32):
    //   hring0 [2][B][H], c0 [B][H], hring1 [2][B][H], c1 [B][H]  => 6*B*H floats (~590 KB)
    float* ws     = (float*)d_ws;
    float* hring0 = ws;
    float* c0     = hring0 + 2 * Bsz * Hh;
    float* hring1 = c0     + 1 * Bsz * Hh;
    float* c1     = hring1 + 2 * Bsz * Hh;

    const size_t state_bytes = (size_t)6 * Bsz * Hh * sizeof(float);
    hipMemsetAsync(d_ws, 0, state_bytes, stream);  // zero h/c state (ws is poisoned 0xAA each call)

    // Pipelined schedule: launch s does layer0@s, layer1@s-1, linear@s-2.
    for (int s = 0; s < Tt + 2; ++s) {
        hipLaunchKernelGGL(lstm_step, dim3(208), dim3(256), 0, stream,
                           x, Wih0, Whh0, bih0, bhh0,
                           Wih1, Whh1, bih1, bhh1,
                           Wlin, blin, out,
                           hring0, c0, hring1, c1, s);
    }
}

// Round 2
// 79195.752 us; speedup vs baseline: 1.2296x; 1.2296x over previous
//
#include <hip/hip_runtime.h>

// Problem constants
#define Bsz   32
#define Tt    1024
#define INF   256
#define Hh    768
#define OUTF  128

// Grid layout: persistent kernel, 196 WGs x 1024 threads, all co-resident
// (capacity is 2 WGs/CU * 256 CUs = 512 >> 196, so plain launch is safe).
#define NWG_L0  96
#define NWG_L1  96
#define NWG_LIN 4
#define NWG     (NWG_L0 + NWG_L1 + NWG_LIN)
#define NTHR    1024

// Workspace layout (float offsets). Total ~656 KB.
#define WS_CNT  0                          // barrier counter (uses 64 floats of pad)
#define WS_XT   64                         // xT ring  [2][256][32]
#define WS_HA   (WS_XT + 2*INF*Bsz)        // hA ring  [2][768][32]  (layer0 output)
#define WS_HB   (WS_HA + 2*Hh*Bsz)         // hB ring  [2][768][32]  (layer1 output)
#define WS_CA   (WS_HB + 2*Hh*Bsz)         // cA       [768][32]
#define WS_CB   (WS_CA + Hh*Bsz)           // cB       [768][32]
#define WS_TOT  (WS_CB + Hh*Bsz)

__device__ __forceinline__ float sigf(float v) { return 1.0f / (1.0f + __expf(-v)); }

// Monotonic-counter grid barrier. Leader-only agent fences give cross-XCD
// release (buffer_wbl2) / acquire (buffer_inv) semantics.
__device__ __forceinline__ void grid_barrier(unsigned* cnt, unsigned target) {
    __syncthreads();   // drains each wave's vmcnt before s_barrier -> all WG stores complete
    if (threadIdx.x == 0) {
        __threadfence();   // release: flush this XCD's L2 to LLC
        __hip_atomic_fetch_add(cnt, 1u, __ATOMIC_RELAXED, __HIP_MEMORY_SCOPE_AGENT);
        while (__hip_atomic_load(cnt, __ATOMIC_RELAXED, __HIP_MEMORY_SCOPE_AGENT) < target) {
            __builtin_amdgcn_s_sleep(1);
        }
        __threadfence();   // acquire: invalidate L1/L2 so fresh h is visible
    }
    __syncthreads();
}

// 4-row dot over a K-chunk. Weight rows: wave-broadcast float4 loads with
// immediate offsets; act (k-major [k][32]): coalesced 128B scalar loads.
template<int CH>
__device__ __forceinline__ void dotrows(const float* __restrict__ w0, const float* __restrict__ w1,
                                        const float* __restrict__ w2, const float* __restrict__ w3,
                                        const float* __restrict__ act, int b,
                                        float& r0, float& r1, float& r2, float& r3)
{
    float a0 = 0.f, a1 = 0.f, a2 = 0.f, a3 = 0.f;
#pragma unroll 8
    for (int kk = 0; kk < CH; kk += 4) {
        float x0 = act[(kk + 0) * Bsz + b];
        float x1 = act[(kk + 1) * Bsz + b];
        float x2 = act[(kk + 2) * Bsz + b];
        float x3 = act[(kk + 3) * Bsz + b];
        float4 q0 = *(const float4*)(w0 + kk);
        float4 q1 = *(const float4*)(w1 + kk);
        float4 q2 = *(const float4*)(w2 + kk);
        float4 q3 = *(const float4*)(w3 + kk);
        a0 += q0.x * x0 + q0.y * x1 + q0.z * x2 + q0.w * x3;
        a1 += q1.x * x0 + q1.y * x1 + q1.z * x2 + q1.w * x3;
        a2 += q2.x * x0 + q2.y * x1 + q2.z * x2 + q2.w * x3;
        a3 += q3.x * x0 + q3.y * x1 + q3.z * x2 + q3.w * x3;
    }
    r0 = a0; r1 = a1; r2 = a2; r3 = a3;
}

__global__ void prologue(const float* __restrict__ x, float* __restrict__ ws) {
    const int gid  = blockIdx.x * blockDim.x + threadIdx.x;
    const int nthr = gridDim.x * blockDim.x;
    // zero barrier counter block
    for (int i = gid; i < 64; i += nthr) ws[WS_CNT + i] = 0.f;
    // zero hA (both parities), hB, cA, cB  (contiguous region)
    for (int i = gid; i < 6 * Hh * Bsz; i += nthr) ws[WS_HA + i] = 0.f;
    // zero xT parity 1 (written during run, but be safe)
    for (int i = gid; i < INF * Bsz; i += nthr) ws[WS_XT + INF * Bsz + i] = 0.f;
    // write xT[0] = transpose of x[:, 0, :]
    for (int i = gid; i < INF * Bsz; i += nthr) {
        int b = i & 31, k = i >> 5;
        ws[WS_XT + i] = x[((size_t)b * Tt + 0) * INF + k];
    }
}

__global__ __launch_bounds__(NTHR) void lstm_persist(
    const float* __restrict__ x,
    const float* __restrict__ Wih0, const float* __restrict__ Whh0,
    const float* __restrict__ bih0, const float* __restrict__ bhh0,
    const float* __restrict__ Wih1, const float* __restrict__ Whh1,
    const float* __restrict__ bih1, const float* __restrict__ bhh1,
    const float* __restrict__ Wlin, const float* __restrict__ blin,
    float* __restrict__ out, float* ws)
{
    __shared__ float part[4096];   // 16 KB partials

    const int wg  = blockIdx.x;
    const int tid = threadIdx.x;
    const int b   = tid & 31;          // batch lane (inner)
    const int sc  = tid >> 8;          // K-chunk 0..3
    const int jq  = (tid >> 5) & 7;    // j-subgroup 0..7

    unsigned* cnt = (unsigned*)(ws + WS_CNT);
    float* xT = ws + WS_XT;
    float* hA = ws + WS_HA;
    float* hB = ws + WS_HB;
    float* cA = ws + WS_CA;
    float* cB = ws + WS_CB;

    // ---- per-role loop-invariant setup ----
    const int roleL0  = (wg < NWG_L0);
    const int roleL1  = (!roleL0 && wg < NWG_L0 + NWG_L1);
    const int roleLIN = (wg >= NWG_L0 + NWG_L1);

    // L0 / L1: jbase and weight row pointers (4 gates) for this thread's chunk
    const float *w0 = nullptr, *w1 = nullptr, *w2 = nullptr, *w3 = nullptr;
    int jbase = 0;
    // gate-phase bias preload (tid<256 threads of L0/L1)
    float bsum0 = 0.f, bsum1 = 0.f, bsum2 = 0.f, bsum3 = 0.f;
    // LIN role
    float blin_r = 0.f;

    if (roleL0) {
        jbase = wg * 8;
        const int jg = jbase + jq;
        if (sc == 0) {      // x-side, K rows of length 256
            w0 = Wih0 + (size_t)(0 * Hh + jg) * INF;
            w1 = Wih0 + (size_t)(1 * Hh + jg) * INF;
            w2 = Wih0 + (size_t)(2 * Hh + jg) * INF;
            w3 = Wih0 + (size_t)(3 * Hh + jg) * INF;
        } else {            // h-side chunk sc-1 of 3, rows of length 768
            const int koff = (sc - 1) * 256;
            w0 = Whh0 + (size_t)(0 * Hh + jg) * Hh + koff;
            w1 = Whh0 + (size_t)(1 * Hh + jg) * Hh + koff;
            w2 = Whh0 + (size_t)(2 * Hh + jg) * Hh + koff;
            w3 = Whh0 + (size_t)(3 * Hh + jg) * Hh + koff;
        }
        if (tid < 256) {
            const int jg2 = jbase + (tid >> 5);
            bsum0 = bih0[0 * Hh + jg2] + bhh0[0 * Hh + jg2];
            bsum1 = bih0[1 * Hh + jg2] + bhh0[1 * Hh + jg2];
            bsum2 = bih0[2 * Hh + jg2] + bhh0[2 * Hh + jg2];
            bsum3 = bih0[3 * Hh + jg2] + bhh0[3 * Hh + jg2];
        }
    } else if (roleL1) {
        jbase = (wg - NWG_L0) * 8;
        const int jg = jbase + jq;
        if (sc < 2) {       // input side = hA, chunk sc of 2 (384 each)
            const int koff = sc * 384;
            w0 = Wih1 + (size_t)(0 * Hh + jg) * Hh + koff;
            w1 = Wih1 + (size_t)(1 * Hh + jg) * Hh + koff;
            w2 = Wih1 + (size_t)(2 * Hh + jg) * Hh + koff;
            w3 = Wih1 + (size_t)(3 * Hh + jg) * Hh + koff;
        } else {            // recurrent side = hB, chunk sc-2 of 2
            const int koff = (sc - 2) * 384;
            w0 = Whh1 + (size_t)(0 * Hh + jg) * Hh + koff;
            w1 = Whh1 + (size_t)(1 * Hh + jg) * Hh + koff;
            w2 = Whh1 + (size_t)(2 * Hh + jg) * Hh + koff;
            w3 = Whh1 + (size_t)(3 * Hh + jg) * Hh + koff;
        }
        if (tid < 256) {
            const int jg2 = jbase + (tid >> 5);
            bsum0 = bih1[0 * Hh + jg2] + bhh1[0 * Hh + jg2];
            bsum1 = bih1[1 * Hh + jg2] + bhh1[1 * Hh + jg2];
            bsum2 = bih1[2 * Hh + jg2] + bhh1[2 * Hh + jg2];
            bsum3 = bih1[3 * Hh + jg2] + bhh1[3 * Hh + jg2];
        }
    } else {
        // LIN: 32 outputs per WG; thread = (sc, og=jq, b); rows o = obase+og*4+c
        const int obase = (wg - NWG_L0 - NWG_L1) * 32;
        const int oc = obase + jq * 4;
        const int koff = sc * 192;
        w0 = Wlin + (size_t)(oc + 0) * Hh + koff;
        w1 = Wlin + (size_t)(oc + 1) * Hh + koff;
        w2 = Wlin + (size_t)(oc + 2) * Hh + koff;
        w3 = Wlin + (size_t)(oc + 3) * Hh + koff;
        blin_r = blin[obase + (tid >> 5)];
    }

    // ---- main time loop: L0@s, L1@s-1, LIN@s-2, one grid barrier per step ----
    for (int s = 0; s < Tt + 2; ++s) {

        // ===== compute phase =====
        if (roleL0 && s < Tt) {
            const int t = s;
            const int pp = (t + 1) & 1;          // parity of h(t-1)
            const float* act = (sc == 0)
                ? (xT + (size_t)(t & 1) * INF * Bsz)
                : (hA + (size_t)pp * Hh * Bsz + (size_t)(sc - 1) * 256 * Bsz);
            float a0, a1, a2, a3;
            dotrows<256>(w0, w1, w2, w3, act, b, a0, a1, a2, a3);
            part[((0 * 8 + jq) * 4 + sc) * 32 + b] = a0;
            part[((1 * 8 + jq) * 4 + sc) * 32 + b] = a1;
            part[((2 * 8 + jq) * 4 + sc) * 32 + b] = a2;
            part[((3 * 8 + jq) * 4 + sc) * 32 + b] = a3;
        } else if (roleL1 && s >= 1 && s <= Tt) {
            const int u = s - 1;
            const float* act = (sc < 2)
                ? (hA + (size_t)(u & 1) * Hh * Bsz + (size_t)sc * 384 * Bsz)
                : (hB + (size_t)((u + 1) & 1) * Hh * Bsz + (size_t)(sc - 2) * 384 * Bsz);
            float a0, a1, a2, a3;
            dotrows<384>(w0, w1, w2, w3, act, b, a0, a1, a2, a3);
            part[((0 * 8 + jq) * 4 + sc) * 32 + b] = a0;
            part[((1 * 8 + jq) * 4 + sc) * 32 + b] = a1;
            part[((2 * 8 + jq) * 4 + sc) * 32 + b] = a2;
            part[((3 * 8 + jq) * 4 + sc) * 32 + b] = a3;
        } else if (roleLIN && s >= 2) {
            const int v = s - 2;
            const float* act = hB + (size_t)(v & 1) * Hh * Bsz + (size_t)sc * 192 * Bsz;
            float a0, a1, a2, a3;
            dotrows<192>(w0, w1, w2, w3, act, b, a0, a1, a2, a3);
            const int ol = jq * 4;
            part[((ol + 0) * 4 + sc) * 32 + b] = a0;
            part[((ol + 1) * 4 + sc) * 32 + b] = a1;
            part[((ol + 2) * 4 + sc) * 32 + b] = a2;
            part[((ol + 3) * 4 + sc) * 32 + b] = a3;
        }

        __syncthreads();

        // ===== gate / output phase =====
        if (roleL0 && s < Tt) {
            const int t = s;
            if (tid < 256) {
                const int j2 = tid >> 5, b2 = tid & 31;
                const int jg2 = jbase + j2;
                float pi = bsum0, pf = bsum1, pg = bsum2, po = bsum3;
#pragma unroll
                for (int q = 0; q < 4; ++q) {
                    pi += part[((0 * 8 + j2) * 4 + q) * 32 + b2];
                    pf += part[((1 * 8 + j2) * 4 + q) * 32 + b2];
                    pg += part[((2 * 8 + j2) * 4 + q) * 32 + b2];
                    po += part[((3 * 8 + j2) * 4 + q) * 32 + b2];
                }
                const float ig = sigf(pi), fg = sigf(pf), gg = tanhf(pg), og = sigf(po);
                const int ci = jg2 * 32 + b2;
                const float cn = fg * cA[ci] + ig * gg;
                cA[ci] = cn;
                hA[(size_t)(t & 1) * Hh * Bsz + ci] = og * tanhf(cn);
            } else if (wg == 0 && (s + 1) < Tt) {
                // stage xT for t+1 (spare 768 threads of WG 0)
                const int pn = (s + 1) & 1;
                for (int idx = tid - 256; idx < 2048; idx += 768) {
                    const int bb = idx >> 6, kq = idx & 63;
                    float4 v = *(const float4*)(x + ((size_t)bb * Tt + (s + 1)) * INF + kq * 4);
                    float* dst = xT + (size_t)pn * INF * Bsz + (size_t)(4 * kq) * Bsz + bb;
                    dst[0 * Bsz] = v.x; dst[1 * Bsz] = v.y; dst[2 * Bsz] = v.z; dst[3 * Bsz] = v.w;
                }
            }
        } else if (roleL1 && s >= 1 && s <= Tt) {
            const int u = s - 1;
            if (tid < 256) {
                const int j2 = tid >> 5, b2 = tid & 31;
                const int jg2 = jbase + j2;
                float pi = bsum0, pf = bsum1, pg = bsum2, po = bsum3;
#pragma unroll
                for (int q = 0; q < 4; ++q) {
                    pi += part[((0 * 8 + j2) * 4 + q) * 32 + b2];
                    pf += part[((1 * 8 + j2) * 4 + q) * 32 + b2];
                    pg += part[((2 * 8 + j2) * 4 + q) * 32 + b2];
                    po += part[((3 * 8 + j2) * 4 + q) * 32 + b2];
                }
                const float ig = sigf(pi), fg = sigf(pf), gg = tanhf(pg), og = sigf(po);
                const int ci = jg2 * 32 + b2;
                const float cn = fg * cB[ci] + ig * gg;
                cB[ci] = cn;
                hB[(size_t)(u & 1) * Hh * Bsz + ci] = og * tanhf(cn);
            }
        } else if (roleLIN && s >= 2) {
            const int v = s - 2;
            const int ol = tid >> 5, bb = tid & 31;
            float acc = blin_r;
#pragma unroll
            for (int q = 0; q < 4; ++q) acc += part[(ol * 4 + q) * 32 + bb];
            const int o = (wg - NWG_L0 - NWG_L1) * 32 + ol;
            out[((size_t)bb * Tt + v) * OUTF + o] = acc;
        }

        grid_barrier(cnt, (unsigned)NWG * (unsigned)(s + 1));
    }
}

extern "C" void kernel_launch(void* const* d_in, const int* in_sizes, int n_in,
                              void* d_out, int out_size, void* d_ws, size_t ws_size,
                              hipStream_t stream)
{
    const float* x    = (const float*)d_in[0];
    const float* Wih0 = (const float*)d_in[1];
    const float* Whh0 = (const float*)d_in[2];
    const float* bih0 = (const float*)d_in[3];
    const float* bhh0 = (const float*)d_in[4];
    const float* Wih1 = (const float*)d_in[5];
    const float* Whh1 = (const float*)d_in[6];
    const float* bih1 = (const float*)d_in[7];
    const float* bhh1 = (const float*)d_in[8];
    const float* Wlin = (const float*)d_in[9];
    const float* blin = (const float*)d_in[10];
    float* out = (float*)d_out;
    float* ws  = (float*)d_ws;   // needs WS_TOT*4 ≈ 656 KB

    hipLaunchKernelGGL(prologue, dim3(128), dim3(256), 0, stream, x, ws);
    hipLaunchKernelGGL(lstm_persist, dim3(NWG), dim3(NTHR), 0, stream,
                       x, Wih0, Whh0, bih0, bhh0,
                       Wih1, Whh1, bih1, bhh1,
                       Wlin, blin, out, ws);
}

// Round 3
// 75180.048 us; speedup vs baseline: 1.2952x; 1.0534x over previous
//
#include <hip/hip_runtime.h>

// Problem constants
#define Tt    1024
#define INF   256
#define Hh    768
#define OUTF  128

// Grid: persistent, 196 WGs x 1024 threads, 1 WG/CU (64 KB LDS), all co-resident.
#define NWG_L0  96
#define NWG_L1  96
#define NWG_LIN 4
#define NWG     196
#define NTHR    1024

typedef unsigned int       u32;
typedef unsigned long long u64;
typedef unsigned short     u16;

// ws layout (bytes):
//   [0,1024)          slots[256] u32   (barrier arrival mailboxes)
//   [1024,1028)       go u32
//   [2048, +98304)    hA ring: [2 parity][32 b][768 j] bf16
//   [100352, +98304)  hB ring: same
#define HPS 24576   // parity stride in u16 elems (32*768)

__device__ __forceinline__ float sigf(float v){ return 1.0f/(1.0f+__expf(-v)); }

__device__ __forceinline__ u16 f2bf(float f){           // round-nearest-even
    u32 u = __float_as_uint(f);
    return (u16)((u + 0x7fffu + ((u>>16)&1u)) >> 16);
}

// L2-bypassing (coherent-at-LLC) accesses for cross-WG data. No fences needed:
// every reader/writer of this data bypasses L1/L2, so nothing stale exists.
__device__ __forceinline__ u64 ld64ws(const u16* p){
    return __hip_atomic_load((const u64*)p, __ATOMIC_RELAXED, __HIP_MEMORY_SCOPE_AGENT);
}
__device__ __forceinline__ void st32ws(u16* p, u32 v){
    __hip_atomic_store((u32*)p, v, __ATOMIC_RELAXED, __HIP_MEMORY_SCOPE_AGENT);
}
__device__ __forceinline__ u32 ldu32(const u32* p){
    return __hip_atomic_load(p, __ATOMIC_RELAXED, __HIP_MEMORY_SCOPE_AGENT);
}
__device__ __forceinline__ void stu32(u32* p, u32 v){
    __hip_atomic_store(p, v, __ATOMIC_RELAXED, __HIP_MEMORY_SCOPE_AGENT);
}

__global__ void prologue(char* ws){
    // zero slots+go+hA+hB : 198656 bytes = 49664 u32
    int i = blockIdx.x * 256 + threadIdx.x;
    if (i < 49664) ((u32*)ws)[i] = 0u;
}

__global__ __launch_bounds__(NTHR) void lstm_persist(
    const float* __restrict__ x,
    const float* __restrict__ Wih0, const float* __restrict__ Whh0,
    const float* __restrict__ bih0, const float* __restrict__ bhh0,
    const float* __restrict__ Wih1, const float* __restrict__ Whh1,
    const float* __restrict__ bih1, const float* __restrict__ bhh1,
    const float* __restrict__ Wlin, const float* __restrict__ blin,
    float* __restrict__ out, char* ws)
{
    // LDS: exactly 64 KB.
    __shared__ u64   act[4096];    // [b(32)][group(128)] of 4 bf16, XOR-swizzled
    __shared__ float part[8192];   // [r(32)][sc(8)][b(32)] fp32 partials

    const int wg  = blockIdx.x;
    const int tid = threadIdx.x;
    const int b   = tid & 31;          // batch lane
    const int rg  = (tid >> 5) & 3;    // gate index (i,f,g,o)
    const int sc  = tid >> 7;          // K-chunk 0..7
    const int xm  = b & 15;            // LDS bank swizzle key

    u32* slots = (u32*)ws;
    u32* go    = (u32*)(ws + 1024);
    u16* hA    = (u16*)(ws + 2048);
    u16* hB    = (u16*)(ws + 2048 + 98304);

    const int role  = (wg < NWG_L0) ? 0 : ((wg < NWG_L0 + NWG_L1) ? 1 : 2);
    const int jbase = (role == 0) ? wg * 8 : ((role == 1) ? (wg - NWG_L0) * 8 : 0);
    const int obase = (role == 2) ? (wg - NWG_L0 - NWG_L1) * 32 : 0;

    // gate-thread state: bias sums + c in registers (thread owns (jl,b) forever)
    float bs0 = 0.f, bs1 = 0.f, bs2 = 0.f, bs3 = 0.f, creg = 0.f, blin_r = 0.f;
    if (role < 2 && tid < 256) {
        const int jg = jbase + (tid >> 5);
        const float* bi = (role == 0) ? bih0 : bih1;
        const float* bh = (role == 0) ? bhh0 : bhh1;
        bs0 = bi[jg]        + bh[jg];
        bs1 = bi[768 + jg]  + bh[768 + jg];
        bs2 = bi[1536 + jg] + bh[1536 + jg];
        bs3 = bi[2304 + jg] + bh[2304 + jg];
    }
    if (role == 2) blin_r = blin[obase + (tid >> 5)];

    for (int s = 0; s < Tt + 2; ++s) {
        bool active; int nch;
        if      (role == 0) { active = (s < Tt);            nch = 2; }
        else if (role == 1) { active = (s >= 1 && s <= Tt); nch = 3; }
        else                { active = (s >= 2);            nch = 2; }

        if (active) {
            float acc[8] = {0.f,0.f,0.f,0.f,0.f,0.f,0.f,0.f};

            for (int c = 0; c < nch; ++c) {
                // ================= stage chunk c into LDS =================
                if (role == 0) {
                    const int t = s;
                    if (c == 0) {
                        // groups 0..63: x[:,t,0..256) fp32 -> bf16
                        {
                            const int k4 = tid & 63, b2 = tid >> 6;   // b2 0..15
                            for (int p = 0; p < 2; ++p) {
                                const int b3 = b2 + p * 16;
                                const float4 xv = *(const float4*)(x + ((size_t)b3 * Tt + t) * INF + k4 * 4);
                                u64 pk = (u64)f2bf(xv.x) | ((u64)f2bf(xv.y) << 16)
                                       | ((u64)f2bf(xv.z) << 32) | ((u64)f2bf(xv.w) << 48);
                                act[b3 * 128 + (k4 ^ (b3 & 15))] = pk;
                            }
                        }
                        // groups 64..127: hA(prev)[j 0..256)
                        {
                            const int j4 = tid & 63, b2 = tid >> 6;
                            u16* src = hA + (size_t)((t + 1) & 1) * HPS;
                            for (int p = 0; p < 2; ++p) {
                                const int b3 = b2 + p * 16;
                                act[b3 * 128 + ((64 + j4) ^ (b3 & 15))] = ld64ws(&src[b3 * 768 + j4 * 4]);
                            }
                        }
                    } else {
                        // groups 0..127: hA(prev)[j 256..768)
                        const int j4 = tid & 127, b2 = tid >> 7;      // b2 0..7
                        u16* src = hA + (size_t)((s + 1) & 1) * HPS;
                        for (int p = 0; p < 4; ++p) {
                            const int b3 = b2 + p * 8;
                            act[b3 * 128 + (j4 ^ (b3 & 15))] = ld64ws(&src[b3 * 768 + 256 + j4 * 4]);
                        }
                    }
                } else if (role == 1) {
                    const int u = s - 1;
                    const int j4 = tid & 127, b2 = tid >> 7;
                    for (int p = 0; p < 4; ++p) {
                        const int b3 = b2 + p * 8;
                        const int k  = c * 512 + j4 * 4;
                        const u16* src = (k < 768)
                            ? (hA + (size_t)(u & 1) * HPS + b3 * 768 + k)
                            : (hB + (size_t)((u + 1) & 1) * HPS + b3 * 768 + (k - 768));
                        act[b3 * 128 + (j4 ^ (b3 & 15))] = ld64ws(src);
                    }
                } else {
                    const u16* base = hB + (size_t)((s - 2) & 1) * HPS;
                    if (c == 0) {
                        const int j4 = tid & 127, b2 = tid >> 7;
                        for (int p = 0; p < 4; ++p) {
                            const int b3 = b2 + p * 8;
                            act[b3 * 128 + (j4 ^ (b3 & 15))] = ld64ws(&base[b3 * 768 + j4 * 4]);
                        }
                    } else {
                        const int j4 = tid & 63, b2 = tid >> 6;
                        for (int p = 0; p < 2; ++p) {
                            const int b3 = b2 + p * 16;
                            act[b3 * 128 + (j4 ^ (b3 & 15))] = ld64ws(&base[b3 * 768 + 512 + j4 * 4]);
                        }
                    }
                }
                __syncthreads();

                // ================= compute chunk c =================
                {
                    int k0, kcnt;
                    const float* wp[8];
                    if (role == 0) {
                        k0 = c * 512 + sc * 64; kcnt = 64;
                        if (k0 < 256) {
                            #pragma unroll
                            for (int i = 0; i < 8; ++i)
                                wp[i] = Wih0 + (size_t)(rg * 768 + jbase + i) * 256 + k0;
                        } else {
                            #pragma unroll
                            for (int i = 0; i < 8; ++i)
                                wp[i] = Whh0 + (size_t)(rg * 768 + jbase + i) * 768 + (k0 - 256);
                        }
                    } else if (role == 1) {
                        k0 = c * 512 + sc * 64; kcnt = 64;
                        if (k0 < 768) {
                            #pragma unroll
                            for (int i = 0; i < 8; ++i)
                                wp[i] = Wih1 + (size_t)(rg * 768 + jbase + i) * 768 + k0;
                        } else {
                            #pragma unroll
                            for (int i = 0; i < 8; ++i)
                                wp[i] = Whh1 + (size_t)(rg * 768 + jbase + i) * 768 + (k0 - 768);
                        }
                    } else {
                        if (c == 0) { k0 = sc * 64;       kcnt = 64; }
                        else        { k0 = 512 + sc * 32; kcnt = 32; }
                        #pragma unroll
                        for (int i = 0; i < 8; ++i)
                            wp[i] = Wlin + (size_t)(obase + rg * 8 + i) * 768 + k0;
                    }
                    const int scg = (k0 - c * 512) >> 2;   // first group within chunk
                    const int ng  = kcnt >> 2;
                    const u64* arow = act + b * 128;

                    for (int gg = 0; gg < ng; ++gg) {
                        const u64 raw = arow[(scg + gg) ^ xm];
                        const u32 lo = (u32)raw, hi = (u32)(raw >> 32);
                        const float a0 = __uint_as_float(lo << 16);
                        const float a1 = __uint_as_float(lo & 0xffff0000u);
                        const float a2 = __uint_as_float(hi << 16);
                        const float a3 = __uint_as_float(hi & 0xffff0000u);
                        #pragma unroll
                        for (int i = 0; i < 8; ++i) {
                            const float4 w = *(const float4*)(wp[i] + gg * 4);
                            acc[i] += w.x * a0 + w.y * a1 + w.z * a2 + w.w * a3;
                        }
                    }
                }
                __syncthreads();
            }

            // write partials: part[r= rg*8+i][sc][b]
            #pragma unroll
            for (int i = 0; i < 8; ++i)
                part[(rg * 8 + i) * 256 + sc * 32 + b] = acc[i];
            __syncthreads();

            // ================= gate / output phase =================
            if (role < 2) {
                if (tid < 256) {
                    const int jl = tid >> 5;
                    float p0 = bs0, p1 = bs1, p2 = bs2, p3 = bs3;
                    #pragma unroll
                    for (int q = 0; q < 8; ++q) {
                        p0 += part[(jl)      * 256 + q * 32 + b];
                        p1 += part[(8 + jl)  * 256 + q * 32 + b];
                        p2 += part[(16 + jl) * 256 + q * 32 + b];
                        p3 += part[(24 + jl) * 256 + q * 32 + b];
                    }
                    const float ig = sigf(p0), fg = sigf(p1);
                    const float gv = tanhf(p2), og = sigf(p3);
                    creg = fg * creg + ig * gv;
                    const float h = og * tanhf(creg);
                    ((u16*)act)[jl * 32 + b] = f2bf(h);
                }
                __syncthreads();
                if (tid < 128) {   // pack j-pairs -> u32 LLC store
                    const int pp = tid >> 5;
                    const u16* hs = (const u16*)act;
                    const u32 val = (u32)hs[(2 * pp) * 32 + b] | ((u32)hs[(2 * pp + 1) * 32 + b] << 16);
                    u16* dst = (role == 0)
                        ? (hA + (size_t)(s & 1) * HPS)
                        : (hB + (size_t)((s - 1) & 1) * HPS);
                    st32ws(dst + b * 768 + jbase + 2 * pp, val);
                }
            } else {
                const int r = tid >> 5, v = s - 2;
                float a = blin_r;
                #pragma unroll
                for (int q = 0; q < 8; ++q) a += part[r * 256 + q * 32 + b];
                out[((size_t)b * Tt + v) * OUTF + obase + r] = a;
            }
        }

        // ================= grid barrier (mailbox, no fences) =================
        __syncthreads();   // drains vmcnt -> this WG's LLC stores are visible
        const u32 tgt = (u32)(s + 1);
        if (wg == 0) {
            if (tid < NWG) {
                if (tid == 0) stu32(slots, tgt);
                int guard = 0;
                while (ldu32(slots + tid) < tgt && guard < (1 << 28)) {
                    __builtin_amdgcn_s_sleep(2); ++guard;
                }
            }
            __syncthreads();
            if (tid == 0) stu32(go, tgt);
        } else {
            if (tid == 0) {
                stu32(slots + wg, tgt);
                int guard = 0;
                while (ldu32(go) < tgt && guard < (1 << 28)) {
                    __builtin_amdgcn_s_sleep(2); ++guard;
                }
            }
            __syncthreads();
        }
    }
}

extern "C" void kernel_launch(void* const* d_in, const int* in_sizes, int n_in,
                              void* d_out, int out_size, void* d_ws, size_t ws_size,
                              hipStream_t stream)
{
    const float* x    = (const float*)d_in[0];
    const float* Wih0 = (const float*)d_in[1];
    const float* Whh0 = (const float*)d_in[2];
    const float* bih0 = (const float*)d_in[3];
    const float* bhh0 = (const float*)d_in[4];
    const float* Wih1 = (const float*)d_in[5];
    const float* Whh1 = (const float*)d_in[6];
    const float* bih1 = (const float*)d_in[7];
    const float* bhh1 = (const float*)d_in[8];
    const float* Wlin = (const float*)d_in[9];
    const float* blin = (const float*)d_in[10];
    float* out = (float*)d_out;
    char*  ws  = (char*)d_ws;   // uses ~200 KB

    hipLaunchKernelGGL(prologue, dim3(194), dim3(256), 0, stream, ws);
    hipLaunchKernelGGL(lstm_persist, dim3(NWG), dim3(NTHR), 0, stream,
                       x, Wih0, Whh0, bih0, bhh0,
                       Wih1, Whh1, bih1, bhh1,
                       Wlin, blin, out, ws);
}